// Round 1
// baseline (220.745 us; speedup 1.0000x reference)
//
#include <hip/hip_runtime.h>

// MHA: B=4, S=1024, E=1024, H=16, D=64.
// cast f32->bf16 + mask bias -> fused QKV GEMM (32x32x16 MFMA, V stored in
// PV-fragment order, XCD-band swizzle) -> flash attention (S^T, no running max)
// -> output GEMM (32x32x16).
// R1: GEMM core double-buffered (T3 minimum 2-phase): stage tile t+1 before
// computing tile t, ONE __syncthreads per K-step (its implicit vmcnt(0) drain
// is the dbuf handshake). 32 -> 16 barriers, global-load latency hidden under
// MFMA.

typedef unsigned short u16;
typedef __bf16 bf16x8 __attribute__((ext_vector_type(8)));
typedef __bf16 bf16x2 __attribute__((ext_vector_type(2)));
typedef short s16x4 __attribute__((ext_vector_type(4)));
typedef float f32x4 __attribute__((ext_vector_type(4)));
typedef float f32x16 __attribute__((ext_vector_type(16)));

struct alignas(8) us4_t { u16 x, y, z, w; };

__device__ __forceinline__ u16 f2bf(float x) {
  unsigned int u = __builtin_bit_cast(unsigned int, x);
  unsigned int r = u + 0x7fffu + ((u >> 16) & 1u);
  return (u16)(r >> 16);
}

__device__ __forceinline__ unsigned int pack2bf(float a, float b) {
#if __has_builtin(__builtin_amdgcn_cvt_pk_bf16_f32)
  bf16x2 r = __builtin_amdgcn_cvt_pk_bf16_f32(a, b);
  return __builtin_bit_cast(unsigned int, r);
#else
  return (unsigned int)f2bf(a) | ((unsigned int)f2bf(b) << 16);
#endif
}

__device__ __forceinline__ f32x4 zero4() {
  f32x4 z; z[0] = 0.f; z[1] = 0.f; z[2] = 0.f; z[3] = 0.f; return z;
}

__device__ __forceinline__ void async_copy16(const void* g, void* l) {
  __builtin_amdgcn_global_load_lds(
      (__attribute__((address_space(1))) void*)(uintptr_t)g,
      (__attribute__((address_space(3))) void*)l, 16, 0, 0);
}

// ---------------- fused cast: 7 tensors + mask->additive bias (log2 domain) ----
__global__ void fused_cast(const float* __restrict__ q, const float* __restrict__ k,
                           const float* __restrict__ v, const float* __restrict__ wq,
                           const float* __restrict__ wk, const float* __restrict__ wv,
                           const float* __restrict__ wo, const int* __restrict__ mask,
                           u16* __restrict__ qo, u16* __restrict__ ko, u16* __restrict__ vo,
                           u16* __restrict__ wqo, u16* __restrict__ wko, u16* __restrict__ wvo,
                           u16* __restrict__ woo, float* __restrict__ biasf) {
  const int blk = blockIdx.x;
  if (blk >= 16384) {
    int i = (blk - 16384) * 256 + threadIdx.x;  // 0..4095
    biasf[i] = mask[i] ? 0.f : -1.4427e20f;
    return;
  }
  const float* src; u16* dst; int off;
  if (blk < 4096)       { src = q;  dst = qo;  off = blk; }
  else if (blk < 8192)  { src = k;  dst = ko;  off = blk - 4096; }
  else if (blk < 12288) { src = v;  dst = vo;  off = blk - 8192; }
  else if (blk < 13312) { src = wq; dst = wqo; off = blk - 12288; }
  else if (blk < 14336) { src = wk; dst = wko; off = blk - 13312; }
  else if (blk < 15360) { src = wv; dst = wvo; off = blk - 14336; }
  else                  { src = wo; dst = woo; off = blk - 15360; }
  const size_t i = (size_t)off * 256 + threadIdx.x;
  float4 f = ((const float4*)src)[i];
  unsigned int lo = pack2bf(f.x, f.y), hi = pack2bf(f.z, f.w);
  unsigned long long pk = (unsigned long long)lo | ((unsigned long long)hi << 32);
  ((unsigned long long*)dst)[i] = pk;
}

// ---------------- GEMM core, 32x32x16 MFMA, double-buffered LDS ---------------
// C[i,o] = sum_e A[i,e]*Bw[o,e] + bias[o].  M-tile 128, N-tile NT*64, BK=64.
// 4 waves (2x2); wave tile 64(m) x NT*32(n) = 2 x NT tiles of 32x32.
// A/B frag: m|n = lane&31, k = (lane>>5)*8 + j.
// C/D frag: col = lane&31, row = (reg&3) + 8*(reg>>2) + 4*(lane>>5).
// Pipeline: prologue stages buf0; each iter issues global_load_lds for
// buf[cur^1] (tile t+1), computes from buf[cur], then one __syncthreads whose
// compiler-emitted vmcnt(0)+lgkmcnt(0) drain publishes buf[cur^1] and retires
// all reads of buf[cur] before any wave re-stages it.
template <bool OUT_BF16, int NT>
__device__ __forceinline__ void gemm_core32(const u16* __restrict__ A,
                                            const u16* __restrict__ Bw,
                                            const float* __restrict__ bias,
                                            void* __restrict__ outp, bool trans,
                                            int m0, int n0) {
  __shared__ u16 lA[2][128 * 64];
  __shared__ u16 lB[2][NT * 64 * 64];
  const int tid = threadIdx.x;
  const int lane = tid & 63, w = tid >> 6;
  const int wm = w >> 1, wn = w & 1;
  const int l32 = lane & 31, hi = lane >> 5;
  const int rg = lane >> 3, cs = lane & 7;

  f32x16 acc[2][NT];
#pragma unroll
  for (int i = 0; i < 2; ++i)
#pragma unroll
    for (int j = 0; j < NT; ++j)
#pragma unroll
      for (int e = 0; e < 16; ++e) acc[i][j][e] = 0.f;

  auto stage = [&](int buf, int it) {
    const int k0 = it * 64;
#pragma unroll
    for (int t = 0; t < 4; ++t) {
      const int row = w * 32 + t * 8 + rg;
      const int c = cs ^ (row & 7);
      async_copy16(A + (size_t)(m0 + row) * 1024 + k0 + c * 8,
                   &lA[buf][(w * 32 + t * 8) * 64]);
    }
#pragma unroll
    for (int t = 0; t < NT * 2; ++t) {
      const int row = w * (NT * 16) + t * 8 + rg;
      const int c = cs ^ (row & 7);
      async_copy16(Bw + (size_t)(n0 + row) * 1024 + k0 + c * 8,
                   &lB[buf][(w * (NT * 16) + t * 8) * 64]);
    }
  };

  stage(0, 0);
  __syncthreads();

  int cur = 0;
  for (int it = 0; it < 16; ++it) {
    if (it < 15) stage(cur ^ 1, it + 1);  // prefetch next tile (in flight across compute)
    const u16* pA = lA[cur];
    const u16* pB = lB[cur];
#pragma unroll
    for (int s = 0; s < 4; ++s) {
      bf16x8 af[2], bfr[NT];
#pragma unroll
      for (int i = 0; i < 2; ++i) {
        const int row = wm * 64 + i * 32 + l32;
        af[i] = *(const bf16x8*)&pA[row * 64 + (((s * 2 + hi) ^ (row & 7)) * 8)];
      }
#pragma unroll
      for (int j = 0; j < NT; ++j) {
        const int row = wn * (NT * 32) + j * 32 + l32;
        bfr[j] = *(const bf16x8*)&pB[row * 64 + (((s * 2 + hi) ^ (row & 7)) * 8)];
      }
#pragma unroll
      for (int i = 0; i < 2; ++i)
#pragma unroll
        for (int j = 0; j < NT; ++j)
          acc[i][j] = __builtin_amdgcn_mfma_f32_32x32x16_bf16(af[i], bfr[j], acc[i][j], 0, 0, 0);
    }
    __syncthreads();  // drains vmcnt(0): buf[cur^1] ready; all reads of buf[cur] retired
    cur ^= 1;
  }

#pragma unroll
  for (int j = 0; j < NT; ++j) {
    const int cg = n0 + wn * (NT * 32) + j * 32 + l32;
    const float bj = bias[cg];
#pragma unroll
    for (int i = 0; i < 2; ++i) {
      const int mbase = m0 + wm * 64 + i * 32 + 4 * hi;
#pragma unroll
      for (int g = 0; g < 4; ++g) {
        const int r0 = mbase + 8 * g;
        if (!trans) {
          if (OUT_BF16) {
            u16* o = (u16*)outp;
#pragma unroll
            for (int rr = 0; rr < 4; ++rr)
              o[(size_t)(r0 + rr) * 1024 + cg] = f2bf(acc[i][j][g * 4 + rr] + bj);
          } else {
            float* o = (float*)outp;
#pragma unroll
            for (int rr = 0; rr < 4; ++rr)
              o[(size_t)(r0 + rr) * 1024 + cg] = acc[i][j][g * 4 + rr] + bj;
          }
        } else {
          // V store in PV-fragment order: Vt2[bh][s>>2][d][s&3]; r0 % 4 == 0.
          u16* o = (u16*)outp;
          const int bh = ((r0 >> 10) << 4) + (cg >> 6);
          const int g2 = (r0 & 1023) >> 2;
          const int d  = cg & 63;
          union { us4_t s; unsigned int u[2]; } pk;
          pk.u[0] = pack2bf(acc[i][j][g * 4 + 0] + bj, acc[i][j][g * 4 + 1] + bj);
          pk.u[1] = pack2bf(acc[i][j][g * 4 + 2] + bj, acc[i][j][g * 4 + 3] + bj);
          *(us4_t*)&o[(size_t)bh * 65536 + g2 * 256 + d * 4] = pk.s;
        }
      }
    }
  }
}

// qkv: grid 768 flat. XCD-band swizzle: xcd = flat&7; each XCD owns 12
// consecutive (m,z) bands; all 8 n-blocks of a band stay on one XCD.
// LDS 64 KiB (dbuf) -> 2 blocks/CU.
__global__ __launch_bounds__(256, 2) void qkv_gemm(
    const u16* __restrict__ Xq, const u16* __restrict__ Xk, const u16* __restrict__ Xv,
    const u16* __restrict__ Wq, const u16* __restrict__ Wk, const u16* __restrict__ Wv,
    const float* __restrict__ bq, const float* __restrict__ bk, const float* __restrict__ bv,
    u16* __restrict__ Qo, u16* __restrict__ Ko, u16* __restrict__ Vto) {
  const int flat = blockIdx.x;
  const int xcd = flat & 7, t = flat >> 3;
  const int n = t & 7, bandl = t >> 3;        // bandl 0..11
  const int band = xcd * 12 + bandl;          // 0..95
  const int z = band >> 5, m = band & 31;
  const u16* A = (z == 0) ? Xq : (z == 1) ? Xk : Xv;
  const u16* W = (z == 0) ? Wq : (z == 1) ? Wk : Wv;
  const float* bias = (z == 0) ? bq : (z == 1) ? bk : bv;
  u16* out = (z == 0) ? Qo : (z == 1) ? Ko : Vto;
  gemm_core32<true, 2>(A, W, bias, out, z == 2, m * 128, n * 128);
}

// out: grid 512 flat; xcd owns 4 m-bands of 16 n-blocks each. LDS 48 KiB (dbuf).
__global__ __launch_bounds__(256, 2) void out_gemm(
    const u16* __restrict__ A, const u16* __restrict__ W,
    const float* __restrict__ bias, float* __restrict__ out) {
  const int flat = blockIdx.x;
  const int xcd = flat & 7, t = flat >> 3;
  const int n = t & 15, m = xcd * 4 + (t >> 4);
  gemm_core32<false, 1>(A, W, bias, out, false, m * 128, n * 64);
}

// ---------------- flash attention, S^T orientation, no running max ------------
__global__ __launch_bounds__(256, 4) void attn_kernel(
    const u16* __restrict__ Qb, const u16* __restrict__ Kb, const u16* __restrict__ Vtb,
    const float* __restrict__ biasf, u16* __restrict__ Ob) {
  __shared__ u16 lK[128 * 64];
  __shared__ u16 lV[64 * 128];  // Vt2 slab, identity layout
  u16* lQ = lV;                 // prologue-only alias

  const int tid = threadIdx.x;
  const int lane = tid & 63, w = tid >> 6;
  const int quad = lane >> 4, l16 = lane & 15;
  const int rg = lane >> 3, cs = lane & 7;

  const int flat = blockIdx.x;
  const int xcd = flat & 7, r = flat >> 3;
  const int bh = xcd * 8 + (r & 7), qt = r >> 3;
  const int b = bh >> 4;
  const size_t qkBase = (size_t)b * 1048576 + (size_t)(bh & 15) * 64;
  const size_t vBase = (size_t)bh * 65536;
  const float C = 0.0450842200277982f;  // (1/sqrt(E)) * log2(e)
  const float* bp = biasf + b * 1024 + quad * 4;

#pragma unroll
  for (int t = 0; t < 2; ++t) {
    const int row = w * 16 + t * 8 + rg;
    const int c = cs ^ (row & 7);
    async_copy16(Qb + qkBase + (size_t)(qt * 64 + row) * 1024 + c * 8,
                 &lQ[(w * 16 + t * 8) * 64]);
  }
  __syncthreads();

  bf16x8 qf[2];
#pragma unroll
  for (int kk = 0; kk < 2; ++kk) {
    const int row = w * 16 + l16;
    qf[kk] = *(const bf16x8*)&lQ[row * 64 + (((kk * 4 + quad) ^ (row & 7)) * 8)];
  }
  __syncthreads();  // protect lQ before lV staging overwrites it

  float lsum = 0.f;
  f32x4 oacc[4];
#pragma unroll
  for (int dt = 0; dt < 4; ++dt) oacc[dt] = zero4();

  for (int it = 0; it < 8; ++it) {
    const int k0 = it * 128;
#pragma unroll
    for (int t = 0; t < 4; ++t) {
      const int row = w * 32 + t * 8 + rg;
      const int c = cs ^ (row & 7);
      async_copy16(Kb + qkBase + (size_t)(k0 + row) * 1024 + c * 8,
                   &lK[(w * 32 + t * 8) * 64]);
    }
#pragma unroll
    for (int t = 0; t < 4; ++t) {
      const int o16 = (w * 4 + t) * 512 + lane * 8;
      async_copy16(Vtb + vBase + (size_t)it * 8192 + o16, &lV[(w * 4 + t) * 512]);
    }
    __syncthreads();

    f32x4 sacc[8];
#pragma unroll
    for (int n = 0; n < 8; ++n) sacc[n] = zero4();
#pragma unroll
    for (int kk = 0; kk < 2; ++kk) {
#pragma unroll
      for (int n = 0; n < 8; ++n) {
        const int row = n * 16 + l16;
        bf16x8 kf = *(const bf16x8*)&lK[row * 64 + (((kk * 4 + quad) ^ (row & 7)) * 8)];
        sacc[n] = __builtin_amdgcn_mfma_f32_16x16x32_bf16(kf, qf[kk], sacc[n], 0, 0, 0);
      }
    }

    f32x4 sum4 = zero4();
#pragma unroll
    for (int n = 0; n < 8; ++n) {
      const float4 vb = *(const float4*)&bp[k0 + n * 16];
      sacc[n][0] = __builtin_amdgcn_exp2f(fmaf(sacc[n][0], C, vb.x));
      sacc[n][1] = __builtin_amdgcn_exp2f(fmaf(sacc[n][1], C, vb.y));
      sacc[n][2] = __builtin_amdgcn_exp2f(fmaf(sacc[n][2], C, vb.z));
      sacc[n][3] = __builtin_amdgcn_exp2f(fmaf(sacc[n][3], C, vb.w));
      sum4[0] += sacc[n][0]; sum4[1] += sacc[n][1];
      sum4[2] += sacc[n][2]; sum4[3] += sacc[n][3];
    }
    float rs = (sum4[0] + sum4[1]) + (sum4[2] + sum4[3]);
    rs += __shfl_xor(rs, 16);
    rs += __shfl_xor(rs, 32);
    lsum += rs;

    s16x4 pf[8];
#pragma unroll
    for (int n = 0; n < 8; ++n) {
      union { s16x4 v; unsigned int u[2]; } pu;
      pu.u[0] = pack2bf(sacc[n][0], sacc[n][1]);
      pu.u[1] = pack2bf(sacc[n][2], sacc[n][3]);
      pf[n] = pu.v;
    }

#pragma unroll
    for (int dt = 0; dt < 4; ++dt) {
      const int dbase = (dt * 16 + l16) * 4;
#pragma unroll
      for (int ks = 0; ks < 8; ++ks) {
        s16x4 vf = *(const s16x4*)&lV[(ks * 4 + quad) * 256 + dbase];
        oacc[dt] = __builtin_amdgcn_mfma_f32_16x16x16bf16_1k(vf, pf[ks], oacc[dt], 0, 0, 0);
      }
    }
    __syncthreads();
  }

  const float inv = 1.f / lsum;
  const int qg = qt * 64 + w * 16 + l16;
#pragma unroll
  for (int dt = 0; dt < 4; ++dt) {
    union { us4_t s; unsigned int u[2]; } pk;
    pk.u[0] = pack2bf(oacc[dt][0] * inv, oacc[dt][1] * inv);
    pk.u[1] = pack2bf(oacc[dt][2] * inv, oacc[dt][3] * inv);
    *(us4_t*)&Ob[qkBase + (size_t)qg * 1024 + dt * 16 + quad * 4] = pk.s;
  }
}

extern "C" void kernel_launch(void* const* d_in, const int* in_sizes, int n_in,
                              void* d_out, int out_size, void* d_ws, size_t ws_size,
                              hipStream_t stream) {
  const float* value  = (const float*)d_in[0];
  const float* key_in = (const float*)d_in[1];
  const float* query  = (const float*)d_in[2];
  const int*   mask   = (const int*)d_in[3];
  const float* Wq = (const float*)d_in[4];
  const float* bq = (const float*)d_in[5];
  const float* Wk = (const float*)d_in[6];
  const float* bk = (const float*)d_in[7];
  const float* Wv = (const float*)d_in[8];
  const float* bv = (const float*)d_in[9];
  const float* Wo = (const float*)d_in[10];
  const float* bo = (const float*)d_in[11];

  u16* ws = (u16*)d_ws;
  u16* q_bf  = ws;              // 4096x1024
  u16* k_bf  = ws + 4194304;
  u16* v_bf  = ws + 8388608;
  u16* wq_bf = ws + 12582912;   // 1024x1024 each
  u16* wk_bf = ws + 13631488;
  u16* wv_bf = ws + 14680064;
  u16* wo_bf = ws + 15728640;
  u16* Qbuf  = ws + 16777216;   // (b,s,h*64+d)
  u16* Kbuf  = ws + 20971520;
  u16* Vtbuf = ws + 25165824;   // Vt2[bh][s>>2][d][s&3]
  u16* attnb = ws + 29360128;   // (b,s,h*64+d)
  float* biasf = (float*)d_out; // consumed by attn, then overwritten by out_gemm

  fused_cast<<<16400, 256, 0, stream>>>(query, key_in, value, Wq, Wk, Wv, Wo, mask,
                                        q_bf, k_bf, v_bf, wq_bf, wk_bf, wv_bf, wo_bf,
                                        biasf);
  qkv_gemm<<<dim3(768), 256, 0, stream>>>(q_bf, k_bf, v_bf, wq_bf, wk_bf, wv_bf,
                                          bq, bk, bv, Qbuf, Kbuf, Vtbuf);
  attn_kernel<<<dim3(1024), 256, 0, stream>>>(Qbuf, Kbuf, Vtbuf, biasf, attnb);
  out_gemm<<<dim3(512), 256, 0, stream>>>(attnb, wo_bf, bo, (float*)d_out);
}

// Round 2
// 205.618 us; speedup vs baseline: 1.0736x; 1.0736x over previous
//
#include <hip/hip_runtime.h>

// MHA: B=4, S=1024, E=1024, H=16, D=64.
// cast f32->bf16 + mask bias -> fused QKV GEMM (256x256 tile, 4-phase/K-tile
// interleaved schedule, 16x16x32 MFMA, dbuf LDS, V stored in PV-fragment
// order, XCD swizzle) -> flash attention (S^T, no running max) -> output GEMM
// (128x128 single-buffer 32x32x16 core).
// R2: qkv ported to the 256-sq deep-pipeline template (T3-style): raw
// s_barrier phases, setprio around MFMA clusters, staging front-loaded in
// phases 1-3, ONE __syncthreads (full drain) per K-tile as dbuf handshake.
// out_gemm reverted to the R0 2-barrier single-buffer core (R1 dbuf regressed:
// 2-phase without phase-interleave is null-to-negative, guide m230).

typedef unsigned short u16;
typedef __bf16 bf16x8 __attribute__((ext_vector_type(8)));
typedef __bf16 bf16x2 __attribute__((ext_vector_type(2)));
typedef short s16x4 __attribute__((ext_vector_type(4)));
typedef float f32x4 __attribute__((ext_vector_type(4)));
typedef float f32x16 __attribute__((ext_vector_type(16)));

struct alignas(8) us4_t { u16 x, y, z, w; };

__device__ __forceinline__ u16 f2bf(float x) {
  unsigned int u = __builtin_bit_cast(unsigned int, x);
  unsigned int r = u + 0x7fffu + ((u >> 16) & 1u);
  return (u16)(r >> 16);
}

__device__ __forceinline__ unsigned int pack2bf(float a, float b) {
#if __has_builtin(__builtin_amdgcn_cvt_pk_bf16_f32)
  bf16x2 r = __builtin_amdgcn_cvt_pk_bf16_f32(a, b);
  return __builtin_bit_cast(unsigned int, r);
#else
  return (unsigned int)f2bf(a) | ((unsigned int)f2bf(b) << 16);
#endif
}

__device__ __forceinline__ f32x4 zero4() {
  f32x4 z; z[0] = 0.f; z[1] = 0.f; z[2] = 0.f; z[3] = 0.f; return z;
}

__device__ __forceinline__ void async_copy16(const void* g, void* l) {
  __builtin_amdgcn_global_load_lds(
      (__attribute__((address_space(1))) void*)(uintptr_t)g,
      (__attribute__((address_space(3))) void*)l, 16, 0, 0);
}

// ---------------- fused cast: 7 tensors + mask->additive bias (log2 domain) ----
__global__ void fused_cast(const float* __restrict__ q, const float* __restrict__ k,
                           const float* __restrict__ v, const float* __restrict__ wq,
                           const float* __restrict__ wk, const float* __restrict__ wv,
                           const float* __restrict__ wo, const int* __restrict__ mask,
                           u16* __restrict__ qo, u16* __restrict__ ko, u16* __restrict__ vo,
                           u16* __restrict__ wqo, u16* __restrict__ wko, u16* __restrict__ wvo,
                           u16* __restrict__ woo, float* __restrict__ biasf) {
  const int blk = blockIdx.x;
  if (blk >= 16384) {
    int i = (blk - 16384) * 256 + threadIdx.x;  // 0..4095
    biasf[i] = mask[i] ? 0.f : -1.4427e20f;
    return;
  }
  const float* src; u16* dst; int off;
  if (blk < 4096)       { src = q;  dst = qo;  off = blk; }
  else if (blk < 8192)  { src = k;  dst = ko;  off = blk - 4096; }
  else if (blk < 12288) { src = v;  dst = vo;  off = blk - 8192; }
  else if (blk < 13312) { src = wq; dst = wqo; off = blk - 12288; }
  else if (blk < 14336) { src = wk; dst = wko; off = blk - 13312; }
  else if (blk < 15360) { src = wv; dst = wvo; off = blk - 14336; }
  else                  { src = wo; dst = woo; off = blk - 15360; }
  const size_t i = (size_t)off * 256 + threadIdx.x;
  float4 f = ((const float4*)src)[i];
  unsigned int lo = pack2bf(f.x, f.y), hi = pack2bf(f.z, f.w);
  unsigned long long pk = (unsigned long long)lo | ((unsigned long long)hi << 32);
  ((unsigned long long*)dst)[i] = pk;
}

// ---------------- qkv GEMM: 256x256 tile, 4-phase deep pipeline ---------------
// C[i,o] = sum_e A[i,e]*W[o,e] + bias[o].  BM=BN=256, BK=64, 512 thr = 8 waves
// (2m x 4n), per-wave output 128x64 = 8x4 frags of 16x16, MFMA 16x16x32 bf16.
// A/B operand frag: row = lane&15, k-chunk(8) = ks*4 + (lane>>4).
// C/D frag: col = lane&15, row = (lane>>4)*4 + reg.
// LDS [2][256][64] for A and B (128 KiB), chunk-XOR swizzle c ^= row&7,
// written linearly by global_load_lds with pre-swizzled global source.
// Per K-tile: 4 phases = quadrants (mh,nh) of the wave tile; phases 1-3 also
// stage next tile's half-tiles (A0+A1, B0, B1) so every load gets >=1.5 phases
// of MFMA cover; tile boundary = __syncthreads (vmcnt0 drain = dbuf handshake).
__global__ __launch_bounds__(512, 2) void qkv_gemm256(
    const u16* __restrict__ Xq, const u16* __restrict__ Xk, const u16* __restrict__ Xv,
    const u16* __restrict__ Wq, const u16* __restrict__ Wk, const u16* __restrict__ Wv,
    const float* __restrict__ bq, const float* __restrict__ bk, const float* __restrict__ bv,
    u16* __restrict__ Qo, u16* __restrict__ Ko, u16* __restrict__ Vto) {
  __shared__ u16 lA[2][256 * 64];
  __shared__ u16 lB[2][256 * 64];

  const int tid = threadIdx.x;
  const int lane = tid & 63, w = tid >> 6;   // w 0..7
  const int wm = w >> 2, wn = w & 3;         // 2 x 4 waves
  const int l16 = lane & 15, q4 = lane >> 4;
  const int rg = lane >> 3, cs = lane & 7;

  // XCD swizzle: 192 blocks, 24 per XCD (6 m-tiles x 4 n) — bijective.
  const int flat = blockIdx.x;
  const int xcd = flat & 7, t = flat >> 3;   // t 0..23
  const int g = xcd * 24 + t;                // 0..191
  const int mt = g >> 2, n = g & 3;          // mt 0..47
  const int z = mt >> 4, m = mt & 15;
  const u16* A = (z == 0) ? Xq : (z == 1) ? Xk : Xv;
  const u16* W = (z == 0) ? Wq : (z == 1) ? Wk : Wv;
  const float* bias = (z == 0) ? bq : (z == 1) ? bk : bv;
  u16* out = (z == 0) ? Qo : (z == 1) ? Ko : Vto;
  const bool trans = (z == 2);
  const int m0 = m * 256, n0 = n * 256;

  f32x4 acc[8][4];
#pragma unroll
  for (int i = 0; i < 8; ++i)
#pragma unroll
    for (int j = 0; j < 4; ++j) acc[i][j] = zero4();

  // Stage one 128-row half-tile slice: 2 gloads/wave, 8 rows each.
  auto stageA = [&](int nxt, int k0) {  // both A halves: 4 gloads/wave
#pragma unroll
    for (int h = 0; h < 2; ++h)
#pragma unroll
      for (int q = 0; q < 2; ++q) {
        const int r0 = h * 128 + (q * 8 + w) * 8;
        const int gr = r0 + rg;
        const int c = cs ^ (gr & 7);
        async_copy16(A + (size_t)(m0 + gr) * 1024 + k0 + c * 8, &lA[nxt][r0 * 64]);
      }
  };
  auto stageB = [&](int nxt, int k0, int h) {  // one B half: 2 gloads/wave
#pragma unroll
    for (int q = 0; q < 2; ++q) {
      const int r0 = h * 128 + (q * 8 + w) * 8;
      const int gr = r0 + rg;
      const int c = cs ^ (gr & 7);
      async_copy16(W + (size_t)(n0 + gr) * 1024 + k0 + c * 8, &lB[nxt][r0 * 64]);
    }
  };
  auto rdA = [&](int cur, int mf, int ks) -> bf16x8 {
    const int row = wm * 128 + mf * 16 + l16;
    const int ch = ks * 4 + q4;
    return *(const bf16x8*)&lA[cur][row * 64 + ((ch ^ (row & 7)) * 8)];
  };
  auto rdB = [&](int cur, int nf, int ks) -> bf16x8 {
    const int row = wn * 64 + nf * 16 + l16;
    const int ch = ks * 4 + q4;
    return *(const bf16x8*)&lB[cur][row * 64 + ((ch ^ (row & 7)) * 8)];
  };

  // Prologue: stage tile 0 fully, drain.
  stageA(0, 0);
  stageB(0, 0, 0);
  stageB(0, 0, 1);
  __syncthreads();

  bf16x8 a[4][2], b[4][2];
  for (int kt = 0; kt < 16; ++kt) {
    const int cur = kt & 1, nxt = cur ^ 1;
    const bool hn = (kt < 15);
    const int k1 = (kt + 1) * 64;

    // ---- phase 1: quadrant (mh=0, nh=0); stage next A (both halves)
#pragma unroll
    for (int mf = 0; mf < 4; ++mf) {
      a[mf][0] = rdA(cur, mf, 0);
      a[mf][1] = rdA(cur, mf, 1);
    }
#pragma unroll
    for (int nf = 0; nf < 2; ++nf) {
      b[nf][0] = rdB(cur, nf, 0);
      b[nf][1] = rdB(cur, nf, 1);
    }
    if (hn) stageA(nxt, k1);
    __builtin_amdgcn_s_barrier();
    __builtin_amdgcn_s_setprio(1);
#pragma unroll
    for (int mf = 0; mf < 4; ++mf)
#pragma unroll
      for (int nf = 0; nf < 2; ++nf)
#pragma unroll
        for (int ks = 0; ks < 2; ++ks)
          acc[mf][nf] = __builtin_amdgcn_mfma_f32_16x16x32_bf16(a[mf][ks], b[nf][ks],
                                                                acc[mf][nf], 0, 0, 0);
    __builtin_amdgcn_s_setprio(0);
    __builtin_amdgcn_s_barrier();

    // ---- phase 2: quadrant (mh=0, nh=1); stage next B half 0
#pragma unroll
    for (int nf = 2; nf < 4; ++nf) {
      b[nf][0] = rdB(cur, nf, 0);
      b[nf][1] = rdB(cur, nf, 1);
    }
    if (hn) stageB(nxt, k1, 0);
    __builtin_amdgcn_s_barrier();
    __builtin_amdgcn_s_setprio(1);
#pragma unroll
    for (int mf = 0; mf < 4; ++mf)
#pragma unroll
      for (int nf = 2; nf < 4; ++nf)
#pragma unroll
        for (int ks = 0; ks < 2; ++ks)
          acc[mf][nf] = __builtin_amdgcn_mfma_f32_16x16x32_bf16(a[mf][ks], b[nf][ks],
                                                                acc[mf][nf], 0, 0, 0);
    __builtin_amdgcn_s_setprio(0);
    __builtin_amdgcn_s_barrier();

    // ---- phase 3: quadrant (mh=1, nh=0); stage next B half 1
#pragma unroll
    for (int mf = 0; mf < 4; ++mf) {
      a[mf][0] = rdA(cur, 4 + mf, 0);
      a[mf][1] = rdA(cur, 4 + mf, 1);
    }
    if (hn) stageB(nxt, k1, 1);
    __builtin_amdgcn_s_barrier();
    __builtin_amdgcn_s_setprio(1);
#pragma unroll
    for (int mf = 0; mf < 4; ++mf)
#pragma unroll
      for (int nf = 0; nf < 2; ++nf)
#pragma unroll
        for (int ks = 0; ks < 2; ++ks)
          acc[4 + mf][nf] = __builtin_amdgcn_mfma_f32_16x16x32_bf16(a[mf][ks], b[nf][ks],
                                                                    acc[4 + mf][nf], 0, 0, 0);
    // ---- phase 4: quadrant (mh=1, nh=1) — all frags in regs, long MFMA tail
#pragma unroll
    for (int mf = 0; mf < 4; ++mf)
#pragma unroll
      for (int nf = 2; nf < 4; ++nf)
#pragma unroll
        for (int ks = 0; ks < 2; ++ks)
          acc[4 + mf][nf] = __builtin_amdgcn_mfma_f32_16x16x32_bf16(a[mf][ks], b[nf][ks],
                                                                    acc[4 + mf][nf], 0, 0, 0);
    __builtin_amdgcn_s_setprio(0);
    // Tile boundary: full drain (vmcnt0+lgkmcnt0) + barrier publishes buf[nxt]
    // and retires all reads of buf[cur] before it is restaged.
    __syncthreads();
    __builtin_amdgcn_sched_barrier(0);
  }

  // ---- epilogue ----
  const int colbase = n0 + wn * 64;
#pragma unroll
  for (int nf = 0; nf < 4; ++nf) {
    const int cg = colbase + nf * 16 + l16;
    const float bj = bias[cg];
#pragma unroll
    for (int mf = 0; mf < 8; ++mf) {
      const int r0 = m0 + wm * 128 + mf * 16 + q4 * 4;
      if (!trans) {
#pragma unroll
        for (int rr = 0; rr < 4; ++rr)
          out[(size_t)(r0 + rr) * 1024 + cg] = f2bf(acc[mf][nf][rr] + bj);
      } else {
        // V store in PV-fragment order: Vt2[bh][s>>2][d][s&3]; r0 % 4 == 0.
        const int bh = ((r0 >> 10) << 4) + (cg >> 6);
        const int g2 = (r0 & 1023) >> 2;
        const int d = cg & 63;
        union { us4_t s; unsigned int u[2]; } pk;
        pk.u[0] = pack2bf(acc[mf][nf][0] + bj, acc[mf][nf][1] + bj);
        pk.u[1] = pack2bf(acc[mf][nf][2] + bj, acc[mf][nf][3] + bj);
        *(us4_t*)&out[(size_t)bh * 65536 + g2 * 256 + d * 4] = pk.s;
      }
    }
  }
}

// ---------------- 128x128 GEMM core (R0 single-buffer), used by out_gemm -----
// C/D frag: col = lane&31, row = (reg&3) + 8*(reg>>2) + 4*(lane>>5).
template <bool OUT_BF16, int NT>
__device__ __forceinline__ void gemm_core32(const u16* __restrict__ A,
                                            const u16* __restrict__ Bw,
                                            const float* __restrict__ bias,
                                            void* __restrict__ outp, bool trans,
                                            int m0, int n0) {
  __shared__ u16 lA[128 * 64];
  __shared__ u16 lB[NT * 64 * 64];
  const int tid = threadIdx.x;
  const int lane = tid & 63, w = tid >> 6;
  const int wm = w >> 1, wn = w & 1;
  const int l32 = lane & 31, hi = lane >> 5;
  const int rg = lane >> 3, cs = lane & 7;

  f32x16 acc[2][NT];
#pragma unroll
  for (int i = 0; i < 2; ++i)
#pragma unroll
    for (int j = 0; j < NT; ++j)
#pragma unroll
      for (int e = 0; e < 16; ++e) acc[i][j][e] = 0.f;

  for (int it = 0; it < 16; ++it) {
    const int k0 = it * 64;
#pragma unroll
    for (int t = 0; t < 4; ++t) {
      const int row = w * 32 + t * 8 + rg;
      const int c = cs ^ (row & 7);
      async_copy16(A + (size_t)(m0 + row) * 1024 + k0 + c * 8, &lA[(w * 32 + t * 8) * 64]);
    }
#pragma unroll
    for (int t = 0; t < NT * 2; ++t) {
      const int row = w * (NT * 16) + t * 8 + rg;
      const int c = cs ^ (row & 7);
      async_copy16(Bw + (size_t)(n0 + row) * 1024 + k0 + c * 8,
                   &lB[(w * (NT * 16) + t * 8) * 64]);
    }
    __syncthreads();
#pragma unroll
    for (int s = 0; s < 4; ++s) {
      bf16x8 af[2], bfr[NT];
#pragma unroll
      for (int i = 0; i < 2; ++i) {
        const int row = wm * 64 + i * 32 + l32;
        af[i] = *(const bf16x8*)&lA[row * 64 + (((s * 2 + hi) ^ (row & 7)) * 8)];
      }
#pragma unroll
      for (int j = 0; j < NT; ++j) {
        const int row = wn * (NT * 32) + j * 32 + l32;
        bfr[j] = *(const bf16x8*)&lB[row * 64 + (((s * 2 + hi) ^ (row & 7)) * 8)];
      }
#pragma unroll
      for (int i = 0; i < 2; ++i)
#pragma unroll
        for (int j = 0; j < NT; ++j)
          acc[i][j] = __builtin_amdgcn_mfma_f32_32x32x16_bf16(af[i], bfr[j], acc[i][j], 0, 0, 0);
    }
    __syncthreads();
  }

#pragma unroll
  for (int j = 0; j < NT; ++j) {
    const int cg = n0 + wn * (NT * 32) + j * 32 + l32;
    const float bj = bias[cg];
#pragma unroll
    for (int i = 0; i < 2; ++i) {
      const int mbase = m0 + wm * 64 + i * 32 + 4 * hi;
#pragma unroll
      for (int g = 0; g < 4; ++g) {
        const int r0 = mbase + 8 * g;
        if (!trans) {
          if (OUT_BF16) {
            u16* o = (u16*)outp;
#pragma unroll
            for (int rr = 0; rr < 4; ++rr)
              o[(size_t)(r0 + rr) * 1024 + cg] = f2bf(acc[i][j][g * 4 + rr] + bj);
          } else {
            float* o = (float*)outp;
#pragma unroll
            for (int rr = 0; rr < 4; ++rr)
              o[(size_t)(r0 + rr) * 1024 + cg] = acc[i][j][g * 4 + rr] + bj;
          }
        } else {
          u16* o = (u16*)outp;
          const int bh = ((r0 >> 10) << 4) + (cg >> 6);
          const int g2 = (r0 & 1023) >> 2;
          const int d  = cg & 63;
          union { us4_t s; unsigned int u[2]; } pk;
          pk.u[0] = pack2bf(acc[i][j][g * 4 + 0] + bj, acc[i][j][g * 4 + 1] + bj);
          pk.u[1] = pack2bf(acc[i][j][g * 4 + 2] + bj, acc[i][j][g * 4 + 3] + bj);
          *(us4_t*)&o[(size_t)bh * 65536 + g2 * 256 + d * 4] = pk.s;
        }
      }
    }
  }
}

// out: grid 512 flat; xcd owns 4 m-bands of 16 n-blocks each.
__global__ __launch_bounds__(256, 3) void out_gemm(
    const u16* __restrict__ A, const u16* __restrict__ W,
    const float* __restrict__ bias, float* __restrict__ out) {
  const int flat = blockIdx.x;
  const int xcd = flat & 7, t = flat >> 3;
  const int n = t & 15, m = xcd * 4 + (t >> 4);
  gemm_core32<false, 1>(A, W, bias, out, false, m * 128, n * 64);
}

// ---------------- flash attention, S^T orientation, no running max ------------
__global__ __launch_bounds__(256, 4) void attn_kernel(
    const u16* __restrict__ Qb, const u16* __restrict__ Kb, const u16* __restrict__ Vtb,
    const float* __restrict__ biasf, u16* __restrict__ Ob) {
  __shared__ u16 lK[128 * 64];
  __shared__ u16 lV[64 * 128];  // Vt2 slab, identity layout
  u16* lQ = lV;                 // prologue-only alias

  const int tid = threadIdx.x;
  const int lane = tid & 63, w = tid >> 6;
  const int quad = lane >> 4, l16 = lane & 15;
  const int rg = lane >> 3, cs = lane & 7;

  const int flat = blockIdx.x;
  const int xcd = flat & 7, r = flat >> 3;
  const int bh = xcd * 8 + (r & 7), qt = r >> 3;
  const int b = bh >> 4;
  const size_t qkBase = (size_t)b * 1048576 + (size_t)(bh & 15) * 64;
  const size_t vBase = (size_t)bh * 65536;
  const float C = 0.0450842200277982f;  // (1/sqrt(E)) * log2(e)
  const float* bp = biasf + b * 1024 + quad * 4;

#pragma unroll
  for (int t = 0; t < 2; ++t) {
    const int row = w * 16 + t * 8 + rg;
    const int c = cs ^ (row & 7);
    async_copy16(Qb + qkBase + (size_t)(qt * 64 + row) * 1024 + c * 8,
                 &lQ[(w * 16 + t * 8) * 64]);
  }
  __syncthreads();

  bf16x8 qf[2];
#pragma unroll
  for (int kk = 0; kk < 2; ++kk) {
    const int row = w * 16 + l16;
    qf[kk] = *(const bf16x8*)&lQ[row * 64 + (((kk * 4 + quad) ^ (row & 7)) * 8)];
  }
  __syncthreads();  // protect lQ before lV staging overwrites it

  float lsum = 0.f;
  f32x4 oacc[4];
#pragma unroll
  for (int dt = 0; dt < 4; ++dt) oacc[dt] = zero4();

  for (int it = 0; it < 8; ++it) {
    const int k0 = it * 128;
#pragma unroll
    for (int t = 0; t < 4; ++t) {
      const int row = w * 32 + t * 8 + rg;
      const int c = cs ^ (row & 7);
      async_copy16(Kb + qkBase + (size_t)(k0 + row) * 1024 + c * 8,
                   &lK[(w * 32 + t * 8) * 64]);
    }
#pragma unroll
    for (int t = 0; t < 4; ++t) {
      const int o16 = (w * 4 + t) * 512 + lane * 8;
      async_copy16(Vtb + vBase + (size_t)it * 8192 + o16, &lV[(w * 4 + t) * 512]);
    }
    __syncthreads();

    f32x4 sacc[8];
#pragma unroll
    for (int n = 0; n < 8; ++n) sacc[n] = zero4();
#pragma unroll
    for (int kk = 0; kk < 2; ++kk) {
#pragma unroll
      for (int n = 0; n < 8; ++n) {
        const int row = n * 16 + l16;
        bf16x8 kf = *(const bf16x8*)&lK[row * 64 + (((kk * 4 + quad) ^ (row & 7)) * 8)];
        sacc[n] = __builtin_amdgcn_mfma_f32_16x16x32_bf16(kf, qf[kk], sacc[n], 0, 0, 0);
      }
    }

    f32x4 sum4 = zero4();
#pragma unroll
    for (int n = 0; n < 8; ++n) {
      const float4 vb = *(const float4*)&bp[k0 + n * 16];
      sacc[n][0] = __builtin_amdgcn_exp2f(fmaf(sacc[n][0], C, vb.x));
      sacc[n][1] = __builtin_amdgcn_exp2f(fmaf(sacc[n][1], C, vb.y));
      sacc[n][2] = __builtin_amdgcn_exp2f(fmaf(sacc[n][2], C, vb.z));
      sacc[n][3] = __builtin_amdgcn_exp2f(fmaf(sacc[n][3], C, vb.w));
      sum4[0] += sacc[n][0]; sum4[1] += sacc[n][1];
      sum4[2] += sacc[n][2]; sum4[3] += sacc[n][3];
    }
    float rs = (sum4[0] + sum4[1]) + (sum4[2] + sum4[3]);
    rs += __shfl_xor(rs, 16);
    rs += __shfl_xor(rs, 32);
    lsum += rs;

    s16x4 pf[8];
#pragma unroll
    for (int n = 0; n < 8; ++n) {
      union { s16x4 v; unsigned int u[2]; } pu;
      pu.u[0] = pack2bf(sacc[n][0], sacc[n][1]);
      pu.u[1] = pack2bf(sacc[n][2], sacc[n][3]);
      pf[n] = pu.v;
    }

#pragma unroll
    for (int dt = 0; dt < 4; ++dt) {
      const int dbase = (dt * 16 + l16) * 4;
#pragma unroll
      for (int ks = 0; ks < 8; ++ks) {
        s16x4 vf = *(const s16x4*)&lV[(ks * 4 + quad) * 256 + dbase];
        oacc[dt] = __builtin_amdgcn_mfma_f32_16x16x16bf16_1k(vf, pf[ks], oacc[dt], 0, 0, 0);
      }
    }
    __syncthreads();
  }

  const float inv = 1.f / lsum;
  const int qg = qt * 64 + w * 16 + l16;
#pragma unroll
  for (int dt = 0; dt < 4; ++dt) {
    union { us4_t s; unsigned int u[2]; } pk;
    pk.u[0] = pack2bf(oacc[dt][0] * inv, oacc[dt][1] * inv);
    pk.u[1] = pack2bf(oacc[dt][2] * inv, oacc[dt][3] * inv);
    *(us4_t*)&Ob[qkBase + (size_t)qg * 1024 + dt * 16 + quad * 4] = pk.s;
  }
}

extern "C" void kernel_launch(void* const* d_in, const int* in_sizes, int n_in,
                              void* d_out, int out_size, void* d_ws, size_t ws_size,
                              hipStream_t stream) {
  const float* value  = (const float*)d_in[0];
  const float* key_in = (const float*)d_in[1];
  const float* query  = (const float*)d_in[2];
  const int*   mask   = (const int*)d_in[3];
  const float* Wq = (const float*)d_in[4];
  const float* bq = (const float*)d_in[5];
  const float* Wk = (const float*)d_in[6];
  const float* bk = (const float*)d_in[7];
  const float* Wv = (const float*)d_in[8];
  const float* bv = (const float*)d_in[9];
  const float* Wo = (const float*)d_in[10];
  const float* bo = (const float*)d_in[11];

  u16* ws = (u16*)d_ws;
  u16* q_bf  = ws;              // 4096x1024
  u16* k_bf  = ws + 4194304;
  u16* v_bf  = ws + 8388608;
  u16* wq_bf = ws + 12582912;   // 1024x1024 each
  u16* wk_bf = ws + 13631488;
  u16* wv_bf = ws + 14680064;
  u16* wo_bf = ws + 15728640;
  u16* Qbuf  = ws + 16777216;   // (b,s,h*64+d)
  u16* Kbuf  = ws + 20971520;
  u16* Vtbuf = ws + 25165824;   // Vt2[bh][s>>2][d][s&3]
  u16* attnb = ws + 29360128;   // (b,s,h*64+d)
  float* biasf = (float*)d_out; // consumed by attn, then overwritten by out_gemm

  fused_cast<<<16400, 256, 0, stream>>>(query, key_in, value, Wq, Wk, Wv, Wo, mask,
                                        q_bf, k_bf, v_bf, wq_bf, wk_bf, wv_bf, wo_bf,
                                        biasf);
  qkv_gemm256<<<dim3(192), 512, 0, stream>>>(q_bf, k_bf, v_bf, wq_bf, wk_bf, wv_bf,
                                             bq, bk, bv, Qbuf, Kbuf, Vtbuf);
  attn_kernel<<<dim3(1024), 256, 0, stream>>>(Qbuf, Kbuf, Vtbuf, biasf, attnb);
  out_gemm<<<dim3(512), 256, 0, stream>>>(attnb, wo_bf, bo, (float*)d_out);
}